// Round 7
// baseline (38.255 us; speedup 1.0000x reference)
//
#include <hip/hip_runtime.h>

#define B_ 32
#define N_ 4096
#define M_ 32
#define F_ 256
#define A_ 8

typedef float f32x4 __attribute__((ext_vector_type(4)));
typedef int   i32x4 __attribute__((ext_vector_type(4)));

// workspace layout (floats):
//   [0, B*A*F)        anchor_feat  (B,A,F)
//   [B*A*F, +B*A)     e2 = anchor_feat @ (a1-a2)
#define WS_AF 0
#define WS_E2 (B_ * A_ * F_)

// ---- kernel 1: anchor_feat[b,k,:] = fatoms[b, idx[b,k], :] @ W ; e2 ----
// e1 = h@(a1+a2) is provably irrelevant: e[b,n,k] = e1[b,n] + e2[b,k] and
// softmax over k is invariant to the per-row constant e1 (masked entries are
// -1e9 absolute; exp underflows to 0 either way; all-masked -> uniform 1/8).
// So fatoms is only ever read for the A=8 anchor rows per batch.
__global__ __launch_bounds__(256) void anchor_kernel(const float* __restrict__ fatoms,
                                                     const int* __restrict__ anchor_idx,
                                                     const float* __restrict__ W,
                                                     const float* __restrict__ a,
                                                     float* __restrict__ ws) {
    int bk = blockIdx.x;  // b*A_ + k
    int b  = bk / A_;
    int f  = threadIdx.x;
    __shared__ float xs[F_];
    __shared__ float red[F_];
    int idx = anchor_idx[bk];
    xs[f] = fatoms[((size_t)b * N_ + idx) * F_ + f];
    __syncthreads();
    // 16 loads in flight per group; 4 independent FMA chains
    float acc[4] = {0.f, 0.f, 0.f, 0.f};
    for (int i0 = 0; i0 < F_; i0 += 16) {
#pragma unroll
        for (int j = 0; j < 16; ++j)
            acc[j & 3] += xs[i0 + j] * W[(i0 + j) * F_ + f];  // coalesced over f
    }
    float accs = (acc[0] + acc[1]) + (acc[2] + acc[3]);
    ws[WS_AF + bk * F_ + f] = accs;
    red[f] = accs * (a[f] - a[f + F_]);
    __syncthreads();
    for (int s = 128; s > 0; s >>= 1) {
        if (f < s) red[f] += red[f + s];
        __syncthreads();
    }
    if (f == 0) ws[WS_E2 + bk] = red[0];
}

// ---- kernel 2: main kernel — 1 wave per block, 64 rows per wave --------
#define RPW 64

__global__ __launch_bounds__(64) void main_kernel(const int* __restrict__ agraph,
                                                  const int* __restrict__ anchor_idx,
                                                  const float* __restrict__ ws,
                                                  float* __restrict__ out) {
    int lane = threadIdx.x;
    const int chunks_per_batch = N_ / RPW;  // 64
    int b     = blockIdx.x / chunks_per_batch;
    int chunk = blockIdx.x % chunks_per_batch;
    int row0  = chunk * RPW;

    // ---- issue the critical-path agraph loads first (row = row0+lane) ----
    const i32x4* gp = (const i32x4*)(agraph + ((size_t)b * N_ + row0 + lane) * M_);
    i32x4 g[M_ / 4];
#pragma unroll
    for (int j = 0; j < M_ / 4; ++j) g[j] = gp[j];

    const float* af = ws + WS_AF + b * (A_ * F_);
    const float* e2 = ws + WS_E2 + b * A_;

    __shared__ float attn[RPW][A_];

    // per-batch uniforms (scalarized: b is block-uniform)
    int   anch[A_];
    float e2r[A_];
#pragma unroll
    for (int k = 0; k < A_; ++k) {
        anch[k] = anchor_idx[b * A_ + k];
        e2r[k]  = e2[k];
    }
    // E_k = exp(e2_k - max_k e2)  (shared shift; masked-softmax ratios exact)
    float m8 = e2r[0];
#pragma unroll
    for (int k = 1; k < A_; ++k) m8 = fmaxf(m8, e2r[k]);
    float E[A_];
#pragma unroll
    for (int k = 0; k < A_; ++k) E[k] = __expf(e2r[k] - m8);

    // anchor_feat fragment for this lane's 4 features
    f32x4 afr[A_];
#pragma unroll
    for (int k = 0; k < A_; ++k) afr[k] = *(const f32x4*)(af + k * F_ + lane * 4);

    // ---- phase 1: one row per lane (all 64 lanes) ----
    {
        unsigned mk = 0;
#pragma unroll
        for (int j = 0; j < M_ / 4; ++j) {
#pragma unroll
            for (int k = 0; k < A_; ++k) {
                int hit = (g[j].x == anch[k]) | (g[j].y == anch[k]) |
                          (g[j].z == anch[k]) | (g[j].w == anch[k]);
                mk |= hit ? (1u << k) : 0u;
            }
        }
        float p[A_], s = 0.f;
#pragma unroll
        for (int k = 0; k < A_; ++k) { p[k] = (mk & (1u << k)) ? E[k] : 0.f; s += p[k]; }
        if (mk == 0) {  // all masked -> uniform
#pragma unroll
            for (int k = 0; k < A_; ++k) p[k] = 1.f;
            s = 8.f;
        }
        float rinv = __builtin_amdgcn_rcpf(s);
#pragma unroll
        for (int k = 0; k < A_; ++k) attn[lane][k] = p[k] * rinv;
    }
    __syncthreads();  // single-wave block: cheap

    // ---- phase 2: wave writes its 64 rows (1KB/row), 4 rows in flight ----
    size_t base = ((size_t)b * N_ + row0) * F_ + lane * 4;
    for (int r0 = 0; r0 < RPW; r0 += 4) {
        f32x4 o[4];
#pragma unroll
        for (int u = 0; u < 4; ++u) {
            f32x4 pa = *(const f32x4*)&attn[r0 + u][0];  // broadcast reads
            f32x4 pb = *(const f32x4*)&attn[r0 + u][4];
            f32x4 t = pa.x * afr[0];
            t += pa.y * afr[1];
            t += pa.z * afr[2];
            t += pa.w * afr[3];
            t += pb.x * afr[4];
            t += pb.y * afr[5];
            t += pb.z * afr[6];
            t += pb.w * afr[7];
            o[u] = t;
        }
#pragma unroll
        for (int u = 0; u < 4; ++u)
            __builtin_nontemporal_store(o[u], (f32x4*)(out + base + (size_t)(r0 + u) * F_));
    }
}

extern "C" void kernel_launch(void* const* d_in, const int* in_sizes, int n_in,
                              void* d_out, int out_size, void* d_ws, size_t ws_size,
                              hipStream_t stream) {
    const float* fatoms     = (const float*)d_in[0];
    const int*   agraph     = (const int*)d_in[1];
    const int*   anchor_idx = (const int*)d_in[2];
    const float* W          = (const float*)d_in[3];
    const float* a          = (const float*)d_in[4];
    float*       out        = (float*)d_out;
    float*       ws         = (float*)d_ws;

    hipLaunchKernelGGL(anchor_kernel, dim3(B_ * A_), dim3(256), 0, stream,
                       fatoms, anchor_idx, W, a, ws);
    hipLaunchKernelGGL(main_kernel, dim3(B_ * (N_ / RPW)), dim3(64), 0, stream,
                       agraph, anchor_idx, ws, out);
}

// Round 8
// 37.316 us; speedup vs baseline: 1.0252x; 1.0252x over previous
//
#include <hip/hip_runtime.h>

#define B_ 32
#define N_ 4096
#define M_ 32
#define F_ 256
#define A_ 8

typedef float f32x4 __attribute__((ext_vector_type(4)));
typedef int   i32x4 __attribute__((ext_vector_type(4)));

// workspace layout (floats):
//   [0, B*A*F)        anchor_feat  (B,A,F)
//   [B*A*F, +B*A)     e2 = anchor_feat @ (a1-a2)
#define WS_AF 0
#define WS_E2 (B_ * A_ * F_)

// ---- kernel 1: anchor_feat[b,k,:] = fatoms[b, idx[b,k], :] @ W ; e2 ----
// e1 = h@(a1+a2) is provably irrelevant: e[b,n,k] = e1[b,n] + e2[b,k] and
// softmax over k is invariant to the per-row constant e1 (masked entries are
// -1e9 absolute; exp underflows to 0 either way; all-masked -> uniform 1/8).
// So fatoms is only ever read for the A=8 anchor rows per batch.
__global__ __launch_bounds__(256) void anchor_kernel(const float* __restrict__ fatoms,
                                                     const int* __restrict__ anchor_idx,
                                                     const float* __restrict__ W,
                                                     const float* __restrict__ a,
                                                     float* __restrict__ ws) {
    int bk = blockIdx.x;  // b*A_ + k
    int b  = bk / A_;
    int f  = threadIdx.x;
    __shared__ float xs[F_];
    __shared__ float red[F_];
    int idx = anchor_idx[bk];
    xs[f] = fatoms[((size_t)b * N_ + idx) * F_ + f];
    __syncthreads();
    // 16 loads in flight per group; 4 independent FMA chains
    float acc[4] = {0.f, 0.f, 0.f, 0.f};
    for (int i0 = 0; i0 < F_; i0 += 16) {
#pragma unroll
        for (int j = 0; j < 16; ++j)
            acc[j & 3] += xs[i0 + j] * W[(i0 + j) * F_ + f];  // coalesced over f
    }
    float accs = (acc[0] + acc[1]) + (acc[2] + acc[3]);
    ws[WS_AF + bk * F_ + f] = accs;
    red[f] = accs * (a[f] - a[f + F_]);
    __syncthreads();
    for (int s = 128; s > 0; s >>= 1) {
        if (f < s) red[f] += red[f + s];
        __syncthreads();
    }
    if (f == 0) ws[WS_E2 + bk] = red[0];
}

// ---- kernel 2: main kernel — 1 wave per block, 64 rows per wave --------
#define RPW 64

__global__ __launch_bounds__(64) void main_kernel(const int* __restrict__ agraph,
                                                  const int* __restrict__ anchor_idx,
                                                  const float* __restrict__ ws,
                                                  float* __restrict__ out) {
    int lane = threadIdx.x;
    const int chunks_per_batch = N_ / RPW;  // 64
    int b     = blockIdx.x / chunks_per_batch;
    int chunk = blockIdx.x % chunks_per_batch;
    int row0  = chunk * RPW;

    // ---- issue the critical-path agraph loads first (row = row0+lane) ----
    const i32x4* gp = (const i32x4*)(agraph + ((size_t)b * N_ + row0 + lane) * M_);
    i32x4 g[M_ / 4];
#pragma unroll
    for (int j = 0; j < M_ / 4; ++j) g[j] = gp[j];

    const float* af = ws + WS_AF + b * (A_ * F_);
    const float* e2 = ws + WS_E2 + b * A_;

    __shared__ float attn[RPW][A_];

    // per-batch uniforms (b is block-uniform)
    int   anch[A_];
    float e2r[A_];
#pragma unroll
    for (int k = 0; k < A_; ++k) {
        anch[k] = anchor_idx[b * A_ + k];
        e2r[k]  = e2[k];
    }
    // E_k = exp(e2_k - max_k e2)  (shared shift; masked-softmax ratios exact)
    float m8 = e2r[0];
#pragma unroll
    for (int k = 1; k < A_; ++k) m8 = fmaxf(m8, e2r[k]);
    float E[A_];
#pragma unroll
    for (int k = 0; k < A_; ++k) E[k] = __expf(e2r[k] - m8);

    // anchor_feat fragment for this lane's 4 features
    f32x4 afr[A_];
#pragma unroll
    for (int k = 0; k < A_; ++k) afr[k] = *(const f32x4*)(af + k * F_ + lane * 4);

    // ---- phase 1: one row per lane (all 64 lanes) ----
    {
        unsigned mk = 0;
#pragma unroll
        for (int j = 0; j < M_ / 4; ++j) {
#pragma unroll
            for (int k = 0; k < A_; ++k) {
                int hit = (g[j].x == anch[k]) | (g[j].y == anch[k]) |
                          (g[j].z == anch[k]) | (g[j].w == anch[k]);
                mk |= hit ? (1u << k) : 0u;
            }
        }
        float p[A_], s = 0.f;
#pragma unroll
        for (int k = 0; k < A_; ++k) { p[k] = (mk & (1u << k)) ? E[k] : 0.f; s += p[k]; }
        if (mk == 0) {  // all masked -> uniform
#pragma unroll
            for (int k = 0; k < A_; ++k) p[k] = 1.f;
            s = 8.f;
        }
        float rinv = __builtin_amdgcn_rcpf(s);
#pragma unroll
        for (int k = 0; k < A_; ++k) attn[lane][k] = p[k] * rinv;
    }
    __syncthreads();  // single-wave block: cheap

    // ---- phase 2: wave writes its 64 rows (1KB/row), 4 rows in flight ----
    // Plain (cached) stores: the harness fill kernel sustains 7.1 TB/s via the
    // normal write-back path; A/B vs R7's nontemporal stores.
    size_t base = ((size_t)b * N_ + row0) * F_ + lane * 4;
    for (int r0 = 0; r0 < RPW; r0 += 4) {
        f32x4 o[4];
#pragma unroll
        for (int u = 0; u < 4; ++u) {
            f32x4 pa = *(const f32x4*)&attn[r0 + u][0];  // broadcast reads
            f32x4 pb = *(const f32x4*)&attn[r0 + u][4];
            f32x4 t = pa.x * afr[0];
            t += pa.y * afr[1];
            t += pa.z * afr[2];
            t += pa.w * afr[3];
            t += pb.x * afr[4];
            t += pb.y * afr[5];
            t += pb.z * afr[6];
            t += pb.w * afr[7];
            o[u] = t;
        }
#pragma unroll
        for (int u = 0; u < 4; ++u)
            *(f32x4*)(out + base + (size_t)(r0 + u) * F_) = o[u];
    }
}

extern "C" void kernel_launch(void* const* d_in, const int* in_sizes, int n_in,
                              void* d_out, int out_size, void* d_ws, size_t ws_size,
                              hipStream_t stream) {
    const float* fatoms     = (const float*)d_in[0];
    const int*   agraph     = (const int*)d_in[1];
    const int*   anchor_idx = (const int*)d_in[2];
    const float* W          = (const float*)d_in[3];
    const float* a          = (const float*)d_in[4];
    float*       out        = (float*)d_out;
    float*       ws         = (float*)d_ws;

    hipLaunchKernelGGL(anchor_kernel, dim3(B_ * A_), dim3(256), 0, stream,
                       fatoms, anchor_idx, W, a, ws);
    hipLaunchKernelGGL(main_kernel, dim3(B_ * (N_ / RPW)), dim3(64), 0, stream,
                       agraph, anchor_idx, ws, out);
}